// Round 5
// baseline (176.050 us; speedup 1.0000x reference)
//
#include <hip/hip_runtime.h>
#include <math.h>

// Problem constants (B, C, H, W) = (32, 10, 192, 320), fp32.
constexpr int B_ = 32, C_ = 10, H_ = 192, W_ = 320;
constexpr int HW_  = H_ * W_;        // 61440 (divisible by 4)
constexpr int CHW_ = C_ * HW_;       // 614400
constexpr int NPTS = B_ * HW_;       // 1966080 spatial points
constexpr int NV4  = NPTS / 4;       // 491520 float4 points
constexpr int NBLK = NV4 / 256;      // 1920 blocks, exact cover

// Partial-sum slots, ws[slot * NBLK + blk], final weights folded in:
// 0: nv  1: num_pos
// 2: sum pos*(g0-r0)^2*log(safe+EPS)            (pos_term = -this)
// 3: sum neg*r0^2*log(1+EPS-safe)*(1-g0)^4      (neg_term = -this)
// 4: P  = 0.5*s_pos + 0.5*s_const + 0.1*s_h
// 5: V1 = 0.05*s_len1 + 0.5*s_trig1
// 6: V2 = 0.05*s_len2 + 0.5*s_trig2
// loss = focal + (P + min(V1,V2)) / nv
#define NACC 7

__device__ __forceinline__ float sl1f(float d) {
    float ad = fabsf(d);
    return ad < 1.0f ? 0.5f * d * d : ad - 0.5f;
}

// Round-5 experiment: force a TRUE single load epoch. Rounds 1-4 all had
// VGPR_Count 32-56 => compiler sank loads into compute => ~5 serial waitcnt
// epochs/wave => ~4 lines in flight per wave. Here: 20 dwordx4 loads issued
// back-to-back, results held live across sched_barrier(0), compute after.
// __launch_bounds__(256,2): <=128 VGPR cap, 6-8 waves/SIMD allowed.
__global__ __launch_bounds__(256, 2) void loss_main(
    const float* __restrict__ re, const float* __restrict__ gt,
    float* __restrict__ ws)
{
    const int tid = blockIdx.x * 256 + threadIdx.x;
    const int p = tid * 4;
    const int b = p / HW_;
    const int s = p - b * HW_;
    const float* rp = re + (size_t)b * CHW_ + s;
    const float* gp = gt + (size_t)b * CHW_ + s;

    // ---- load epoch: 20 independent coalesced dwordx4 loads ----
    float4 R[10], G[10];
#pragma unroll
    for (int c = 0; c < 10; ++c) {
        R[c] = *(const float4*)(rp + c * HW_);
        G[c] = *(const float4*)(gp + c * HW_);
    }
    // No instruction may cross: keeps all 40 result VGPRs live, preventing
    // the scheduler from splitting the epoch.
    __builtin_amdgcn_sched_barrier(0);

    float acc[NACC];
#pragma unroll
    for (int i = 0; i < NACC; ++i) acc[i] = 0.0f;

#pragma unroll
    for (int j = 0; j < 4; ++j) {
        #define RC(c) (((const float*)&R[c])[j])
        #define GC(c) (((const float*)&G[c])[j])
        const float g = GC(0), r = RC(0);
        const float m = (g == 1.0f) ? 1.0f : 0.0f;
        acc[0] += m;
        const float pos = (g >= 0.1f) ? 1.0f : 0.0f;
        const float neg = ((g >= 0.0f) && (g < 0.1f)) ? 1.0f : 0.0f;
        acc[1] += pos;
        const float safe = fminf(fmaxf(r, 1e-6f), 1.0f - 1e-6f);
        const float d0 = g - r;
        acc[2] += pos * (d0 * d0) * logf(safe + 6e-8f);
        const float omg = 1.0f - g;
        const float omg2 = omg * omg;
        acc[3] += neg * (r * r) * logf(1.0f + 6e-8f - safe) * (omg2 * omg2);

        const float r1 = RC(1), r2 = RC(2), r3 = RC(3), r4v = RC(4);
        const float r5 = RC(5), r6 = RC(6), r7 = RC(7), r8 = RC(8), r9 = RC(9);
        const float g1 = GC(1), g2 = GC(2), g3 = GC(3), g4v = GC(4);
        const float g5 = GC(5), g6 = GC(6), g7 = GC(7), g8 = GC(8), g9 = GC(9);

        // P: 0.5*pos + 0.5*const + 0.1*height
        const float sp = sl1f(r1 - g1) + sl1f(r2 - g2);
        const float c1 = 1.0f - r5 * r5 - r4v * r4v;
        const float c2 = 1.0f - r8 * r8 - r7 * r7;
        const float sc = c1 * c1 + c2 * c2;
        const float sh = sl1f(r9 - g9);
        acc[4] += m * (0.5f * sp + 0.5f * sc + 0.1f * sh);

        // V1: 0.05*len1 + 0.5*trig1
        const float d44 = r4v - g4v, d77 = r7 - g7;
        const float d55 = r5 - g5,  d88 = r8 - g8;
        const float t1 = d44 * d44 + d77 * d77 + d55 * d55 + d88 * d88;
        const float l1 = sl1f(r3 - g3) + sl1f(r6 - g6);
        acc[5] += m * (0.05f * l1 + 0.5f * t1);

        // V2: 0.05*len2 + 0.5*trig2
        const float d47 = r4v - g7, d74 = r7 - g4v;
        const float d58 = r5 - g8,  d85 = r8 - g5;
        const float t2 = d47 * d47 + d74 * d74 + d58 * d58 + d85 * d85;
        const float l2 = sl1f(r3 - g6) + sl1f(r6 - g3);
        acc[6] += m * (0.05f * l2 + 0.5f * t2);
        #undef RC
        #undef GC
    }

    // block reduction: wave shuffle (64 lanes) -> LDS (4 waves) -> plain store
    __shared__ float smem[NACC][4];
    const int lane = threadIdx.x & 63;
    const int wid  = threadIdx.x >> 6;
#pragma unroll
    for (int i = 0; i < NACC; ++i) {
        float v = acc[i];
#pragma unroll
        for (int off = 32; off > 0; off >>= 1) v += __shfl_down(v, off, 64);
        if (lane == 0) smem[i][wid] = v;
    }
    __syncthreads();
    if (threadIdx.x < NACC) {
        const int i = threadIdx.x;
        ws[i * NBLK + blockIdx.x] =
            smem[i][0] + smem[i][1] + smem[i][2] + smem[i][3];
    }
}

// One block, 1024 threads: all 7*1920 partials in one parallel load epoch.
__global__ __launch_bounds__(1024) void loss_reduce(
    const float* __restrict__ ws, float* __restrict__ out)
{
    float acc[NACC];
#pragma unroll
    for (int i = 0; i < NACC; ++i) acc[i] = 0.0f;

#pragma unroll
    for (int k = 0; k < 2; ++k) {
        const int idx = threadIdx.x + k * 1024;
        if (idx < NBLK) {
#pragma unroll
            for (int i = 0; i < NACC; ++i)
                acc[i] += ws[i * NBLK + idx];
        }
    }

    __shared__ float smem[NACC][16];
    const int lane = threadIdx.x & 63;
    const int wid  = threadIdx.x >> 6;
#pragma unroll
    for (int i = 0; i < NACC; ++i) {
        float v = acc[i];
#pragma unroll
        for (int off = 32; off > 0; off >>= 1) v += __shfl_down(v, off, 64);
        if (lane == 0) smem[i][wid] = v;
    }
    __syncthreads();

    if (threadIdx.x == 0) {
        float slot[NACC];
#pragma unroll
        for (int i = 0; i < NACC; ++i) {
            float v = 0.0f;
#pragma unroll
            for (int w = 0; w < 16; ++w) v += smem[i][w];
            slot[i] = v;
        }
        const float nv    = slot[0];
        const float npos  = slot[1];
        const float pterm = -slot[2];
        const float nterm = -slot[3];
        const float focal = (npos == 0.0f) ? nterm : (pterm + nterm) / npos;
        out[0] = focal + (slot[4] + fminf(slot[5], slot[6])) / nv;
    }
}

extern "C" void kernel_launch(void* const* d_in, const int* in_sizes, int n_in,
                              void* d_out, int out_size, void* d_ws, size_t ws_size,
                              hipStream_t stream)
{
    const float* re = (const float*)d_in[0];
    const float* gt = (const float*)d_in[1];
    float* ws  = (float*)d_ws;
    float* out = (float*)d_out;

    loss_main<<<NBLK, 256, 0, stream>>>(re, gt, ws);
    loss_reduce<<<1, 1024, 0, stream>>>(ws, out);
}